// Round 7
// baseline (552.646 us; speedup 1.0000x reference)
//
#include <hip/hip_runtime.h>
#include <cstdint>
#include <cstddef>

typedef __bf16 bf16;
typedef __bf16 bf16x8 __attribute__((ext_vector_type(8)));
typedef float f32x4 __attribute__((ext_vector_type(4)));

#define DEV static __device__ __forceinline__

constexpr int BATCH = 8;
constexpr int SEQ = 4096;
constexpr int DIM = 512;
constexpr int HEADS = 8;
constexpr int DH = 64;
constexpr int WIN = 128;
constexpr int NW = SEQ / WIN;        // 32
constexpr int TOK = BATCH * SEQ;     // 32768
constexpr float EPS = 1e-5f;

// canonical bf16 weights in workspace (element offsets)
constexpr size_t R_EL   = (size_t)TOK * DIM;            // 16,777,216
constexpr size_t C_QKV  = 0;                             // 786432
constexpr size_t C_WOUT = 786432;                        // 262144
constexpr size_t C_WF1  = 1048576;                       // 1048576
constexpr size_t C_WF2  = 2097152;                       // 1048576
constexpr size_t C_SM   = 3145728;                       // 2688 smalls
// smalls: qsc 0, ksc 64, bout 128, l1g 640, l1b 1152, lfg 1664, lfb 2176
constexpr size_t P_EL   = 3148416;                       // slot base (%8==0)

DEV void gload_lds16(const void* g, void* l) {
  __builtin_amdgcn_global_load_lds((__attribute__((address_space(1))) void*)g,
                                   (__attribute__((address_space(3))) void*)l,
                                   16, 0, 0);
}

DEV f32x4 mfma16(bf16x8 a, bf16x8 b, f32x4 c) {
  return __builtin_amdgcn_mfma_f32_16x16x32_bf16(a, b, c, 0, 0, 0);
}

// Branchless exact-GELU via Abramowitz-Stegun 7.1.26 erf approximation.
// |erf error| <= 1.5e-7 (far below bf16 output rounding). ~16 cheap VALU ops,
// no divergence -- vs library erff's two-path implementation.
DEV float fast_gelu(float v) {
  const float z = fabsf(v) * 0.7071067811865476f;
  const float t = __builtin_amdgcn_rcpf(1.0f + 0.3275911f * z);
  const float p = t * (0.254829592f +
                  t * (-0.284496736f +
                  t * (1.421413741f +
                  t * (-1.453152027f +
                  t * 1.061405429f))));
  const float e = __expf(-z * z);
  const float erfa = 1.0f - p * e;               // erf(|v|/sqrt2)
  const float cdf = 0.5f + copysignf(0.5f * erfa, v);
  return v * cdf;
}

// ---------------- ingest: dtype-probe + convert weight inputs to bf16 ----------
struct SrcPtrs { const void* p[12]; };

DEV void copy8(const void* src, long si, bf16* dst, bool f32) {
  if (f32) {
    const float4* s = (const float4*)((const float*)src + si);
    float4 a = s[0], b = s[1];
    bf16x8 o;
    o[0] = (bf16)a.x; o[1] = (bf16)a.y; o[2] = (bf16)a.z; o[3] = (bf16)a.w;
    o[4] = (bf16)b.x; o[5] = (bf16)b.y; o[6] = (bf16)b.z; o[7] = (bf16)b.w;
    *(bf16x8*)dst = o;
  } else {
    *(bf16x8*)dst = *(const bf16x8*)((const bf16*)src + si);
  }
}

__global__ __launch_bounds__(256) void ingest_kernel(SrcPtrs sp, bf16* cano) {
  const bool f32 = (((const unsigned short*)sp.p[2])[0] == 0);
  const long e = (long)threadIdx.x * 8;
  int b = blockIdx.x;
  if (b < 384)  { long o = (long)b * 2048 + e; copy8(sp.p[1], o, cano + C_QKV + o, f32); return; }
  b -= 384;
  if (b < 128)  { long o = (long)b * 2048 + e; copy8(sp.p[4], o, cano + C_WOUT + o, f32); return; }
  b -= 128;
  if (b < 512)  { long o = (long)b * 2048 + e; copy8(sp.p[10], o, cano + C_WF1 + o, f32); return; }
  b -= 512;
  if (b < 512)  { long o = (long)b * 2048 + e; copy8(sp.p[11], o, cano + C_WF2 + o, f32); return; }
  b -= 512;
  const long o = (long)b * 2048 + e;
  if (o >= 2688) return;
  const void* src; long si;
  if      (o < 64)   { src = sp.p[2]; si = o; }
  else if (o < 128)  { src = sp.p[3]; si = o - 64; }
  else if (o < 640)  { src = sp.p[5]; si = o - 128; }
  else if (o < 1152) { src = sp.p[6]; si = o - 640; }
  else if (o < 1664) { src = sp.p[7]; si = o - 1152; }
  else if (o < 2176) { src = sp.p[8]; si = o - 1664; }
  else               { src = sp.p[9]; si = o - 2176; }
  copy8(src, si, cano + C_SM + o, f32);
}

// ---------------- LayerNorm: one wave per 512-dim token ----------------
__global__ __launch_bounds__(256) void ln_kernel(const void* __restrict__ in,
                                                 const bf16* __restrict__ gg,
                                                 const bf16* __restrict__ bb,
                                                 bf16* __restrict__ out,
                                                 const unsigned short* __restrict__ probe,
                                                 int raw) {
  const int wave = threadIdx.x >> 6, lane = threadIdx.x & 63;
  const int row = blockIdx.x * 4 + wave;
  const size_t base = (size_t)row * DIM + lane * 8;
  float f[8];
  if (raw && probe[0] == 0) {
    const float4* p = (const float4*)((const float*)in + base);
    float4 a = p[0], bq = p[1];
    f[0] = a.x; f[1] = a.y; f[2] = a.z; f[3] = a.w;
    f[4] = bq.x; f[5] = bq.y; f[6] = bq.z; f[7] = bq.w;
  } else {
    bf16x8 v = *(const bf16x8*)((const bf16*)in + base);
#pragma unroll
    for (int i = 0; i < 8; ++i) f[i] = (float)v[i];
  }
  float s = 0.f, sq = 0.f;
#pragma unroll
  for (int i = 0; i < 8; ++i) { s += f[i]; sq += f[i] * f[i]; }
#pragma unroll
  for (int m = 32; m; m >>= 1) { s += __shfl_xor(s, m); sq += __shfl_xor(sq, m); }
  const float mean = s * (1.0f / DIM);
  const float var = fmaxf(sq * (1.0f / DIM) - mean * mean, 0.0f);
  const float rs = rsqrtf(var + EPS);
  bf16x8 gv = *(const bf16x8*)(gg + lane * 8);
  bf16x8 bv = *(const bf16x8*)(bb + lane * 8);
  bf16x8 o;
#pragma unroll
  for (int i = 0; i < 8; ++i) o[i] = (bf16)((f[i] - mean) * rs * (float)gv[i] + (float)bv[i]);
  *(bf16x8*)((bf16*)out + base) = o;
}

// ---------------- GEMM: C = A(MxK) @ Bw(N x K, row-stride bstride)^T ----------------
// 256x128 tile, 8 waves (4M x 2N), 3-buffer depth-2 counted-vmcnt pipeline +
// T2 LDS swizzle (proven R6 structure -- see session notes).  Used for QKV
// (MODE 0) and WOUT (MODE 1) only; the FF pair is handled by ffn_fused below.
template <int MODE>
__global__ __launch_bounds__(512) void gemm_bt(const bf16* __restrict__ A,
                                               const bf16* __restrict__ Bw,
                                               bf16* __restrict__ O0, bf16* __restrict__ O1,
                                               bf16* __restrict__ O2,
                                               float* __restrict__ Of,
                                               const void* __restrict__ Xraw,
                                               const bf16* __restrict__ Xb,
                                               const bf16* __restrict__ bias,
                                               const unsigned short* __restrict__ probe,
                                               int K, int bstride, int ostride, int gx) {
  extern __shared__ __align__(16) bf16 smem[];        // 3 * 12288 elems = 72 KiB
  const int tid = threadIdx.x;
  const int wid = tid >> 6, lane = tid & 63;
  const int l15 = lane & 15, quad = lane >> 4;
  const int id = blockIdx.x;
  const int per = gx * 8;
  const int tM = ((id / per) * 8 + (id & 7)) * 256;
  const int tN = ((id % per) >> 3) * 128;
  const int wM = (wid >> 1) * 64, wN = (wid & 1) * 64;
  const int kq = (quad ^ ((l15 >> 1) & 3)) * 8;
  f32x4 acc[4][4];
  const f32x4 z = {0.f, 0.f, 0.f, 0.f};
#pragma unroll
  for (int i = 0; i < 4; ++i)
#pragma unroll
    for (int j = 0; j < 4; ++j) acc[i][j] = z;

  const int cA0 = tid,       rA0 = cA0 >> 2, sA0 = (((cA0 & 3) ^ ((cA0 >> 3) & 3)) * 8);
  const int cA1 = tid + 512, rA1 = cA1 >> 2, sA1 = (((cA1 & 3) ^ ((cA1 >> 3) & 3)) * 8);
  const int cB0 = tid,       rB0 = cB0 >> 2, sB0 = sA0;

  auto stage = [&](int t, int p) {
    const int k0 = t * 32;
    bf16* dA = smem + p * 12288;
    bf16* dB = dA + 8192;
    gload_lds16(A  + (size_t)(tM + rA0) * K       + k0 + sA0, &dA[cA0 * 8]);
    gload_lds16(A  + (size_t)(tM + rA1) * K       + k0 + sA1, &dA[cA1 * 8]);
    gload_lds16(Bw + (size_t)(tN + rB0) * bstride + k0 + sB0, &dB[cB0 * 8]);
  };

  const int nt = K >> 5;
  stage(0, 0);
  stage(1, 1);
  __builtin_amdgcn_sched_barrier(0);
  asm volatile("s_waitcnt vmcnt(3)" ::: "memory");
  __builtin_amdgcn_s_barrier();
  __builtin_amdgcn_sched_barrier(0);

  int cur = 0;
  for (int t = 0; t < nt; ++t) {
    if (t + 2 < nt) {
      int nx = cur + 2; if (nx >= 3) nx -= 3;
      stage(t + 2, nx);
    }
    const bf16* As = smem + cur * 12288;
    const bf16* Bs = As + 8192;
    bf16x8 aF[4], bF[4];
#pragma unroll
    for (int i = 0; i < 4; ++i) aF[i] = *(const bf16x8*)&As[(wM + i * 16 + l15) * 32 + kq];
#pragma unroll
    for (int j = 0; j < 4; ++j) bF[j] = *(const bf16x8*)&Bs[(wN + j * 16 + l15) * 32 + kq];
#pragma unroll
    for (int i = 0; i < 4; ++i)
#pragma unroll
      for (int j = 0; j < 4; ++j) acc[i][j] = mfma16(aF[i], bF[j], acc[i][j]);
    if (t < nt - 1) {
      __builtin_amdgcn_sched_barrier(0);
      if (t + 2 < nt) asm volatile("s_waitcnt vmcnt(3)" ::: "memory");
      else            asm volatile("s_waitcnt vmcnt(0)" ::: "memory");
      __builtin_amdgcn_s_barrier();
      __builtin_amdgcn_sched_barrier(0);
    }
    ++cur; if (cur == 3) cur = 0;
  }
  const int q0 = nt % 3;
  bf16* eb = smem + q0 * 12288;

  if constexpr (MODE == 0) {
    bf16* ob = eb + wid * 1152;
    const int colbase = tN + wN;
    const int which = colbase >> 9;
    const int head = (colbase >> 6) & 7;
    bf16* dst = which == 0 ? O0 : (which == 1 ? O1 : O2);
    const int ch = lane & 7;
    float scv[8], invf[8];
    if (which < 2) {
      const bf16* sc = which ? bias : Xb;             // ksc : qsc
      bf16x8 s8 = *(const bf16x8*)(sc + ch * 8);
#pragma unroll
      for (int u = 0; u < 8; ++u) {
        scv[u] = (float)s8[u] * (which == 0 ? 8.0f : 1.0f);   // fold QK_SCALE into q
        invf[u] = exp2f(-(float)((ch & 3) * 8 + u) * (13.287712379549449f / 32.0f));
      }
    }
#pragma unroll
    for (int i = 0; i < 4; ++i) {
#pragma unroll
      for (int j = 0; j < 4; ++j)
#pragma unroll
        for (int r = 0; r < 4; ++r)
          ob[(quad * 4 + r) * 72 + j * 16 + l15] = (bf16)acc[i][j][r];
#pragma unroll
      for (int t = 0; t < 2; ++t) {
        const int rr = t * 8 + (lane >> 3);
        const int rowg = tM + wM + i * 16 + rr;
        bf16x8 ov = *(const bf16x8*)&ob[rr * 72 + ch * 8];
        float f[8];
#pragma unroll
        for (int u = 0; u < 8; ++u) f[u] = (float)ov[u];
        if (which < 2) {
          float ss = 0.f;
#pragma unroll
          for (int u = 0; u < 8; ++u) ss += f[u] * f[u];
          ss += __shfl_xor(ss, 1); ss += __shfl_xor(ss, 2); ss += __shfl_xor(ss, 4);
          const float rs = 1.0f / fmaxf(sqrtf(ss), 1e-12f);
#pragma unroll
          for (int u = 0; u < 8; ++u) f[u] *= rs * scv[u];
          float pf[8];
#pragma unroll
          for (int u = 0; u < 8; ++u) pf[u] = __shfl_xor(f[u], 4);
          const float pos = (float)(rowg & (SEQ - 1));
#pragma unroll
          for (int u = 0; u < 8; ++u) {
            float sn, cs;
            __sincosf(pos * invf[u], &sn, &cs);
            const float rot = (ch < 4) ? -pf[u] : pf[u];
            f[u] = f[u] * cs + rot * sn;
          }
        }
        bf16x8 o8;
#pragma unroll
        for (int u = 0; u < 8; ++u) o8[u] = (bf16)f[u];
        const int bb = rowg >> 12, n = rowg & (SEQ - 1);
        *(bf16x8*)(dst + ((size_t)(bb * HEADS + head) * SEQ + n) * DH + ch * 8) = o8;
      }
    }
    return;
  }

  if constexpr (MODE == 1) {
    bf16* ob = eb + wid * 1152;
    const int ch = lane & 7;
    bf16x8 bias8 = *(const bf16x8*)(bias + tN + wN + ch * 8);
    const bool xf32 = (probe[0] == 0);
#pragma unroll
    for (int i = 0; i < 4; ++i) {
#pragma unroll
      for (int j = 0; j < 4; ++j)
#pragma unroll
        for (int r = 0; r < 4; ++r)
          ob[(quad * 4 + r) * 72 + j * 16 + l15] = (bf16)acc[i][j][r];
#pragma unroll
      for (int t = 0; t < 2; ++t) {
        const int rr = t * 8 + (lane >> 3);
        const int rowg = tM + wM + i * 16 + rr;
        bf16x8 ov = *(const bf16x8*)&ob[rr * 72 + ch * 8];
        bf16x8 o8;
        const size_t idx = (size_t)rowg * DIM + tN + wN + ch * 8;
        float xr[8];
        if (xf32) {
          const float4* xp = (const float4*)((const float*)Xraw + idx);
          float4 a = xp[0], bq = xp[1];
          xr[0] = a.x; xr[1] = a.y; xr[2] = a.z; xr[3] = a.w;
          xr[4] = bq.x; xr[5] = bq.y; xr[6] = bq.z; xr[7] = bq.w;
        } else {
          bf16x8 xv = *(const bf16x8*)((const bf16*)Xraw + idx);
#pragma unroll
          for (int u = 0; u < 8; ++u) xr[u] = (float)xv[u];
        }
#pragma unroll
        for (int u = 0; u < 8; ++u) o8[u] = (bf16)((float)ov[u] + xr[u] + (float)bias8[u]);
        *(bf16x8*)(O0 + idx) = o8;
      }
    }
    return;
  }
}

// ---------------- fused FFN: out = x2 + gelu(hf @ W1^T) @ W2^T ----------------
// One block = 128 rows x all 512 out cols; 256 blocks = 1/CU; 8 waves.
// Per chunk c (16 chunks of 128 f1-cols):
//   GEMM1 (K=512): f1c[128x128] = hf_rows @ W1[c*128..+128]^T
//     -- proven 3-buffer counted-vmcnt loop (stage h-tile 8KB + W1c-tile 8KB
//        per 16KB buffer, T2 swizzle, vmcnt(2) tails).
//   barA -> GELU(acc1)->bf16 -> f1c (XOR-swizzled 16B slots: slot^=(row&7)),
//   issue next chunk's stages t0,t1 (hidden under GEMM2), lgkm0+barB,
//   GEMM2 (4 k-steps): acc2 += f1c @ W2[:,c-chunk]^T, A from LDS (swizzled),
//     B fragments DIRECT from global (W2 is 2MB, L2-resident),
//   barC (vmcnt(2): next chunk's t0 landed).
// k-accumulation order identical to the unfused FF1->FF2 pair => bit-identical.
// f1 never touches HBM (saves 134MB write + 114MB fetch).
// LDS: 3x16KB stage + 32KB f1c = 81920 B. acc2 = 128 VGPR (64rows x 128cols
// per wave); launch_bounds(512,2) caps at 256 VGPR, 2 waves/SIMD.
// Epilogue: barrier, per-wave f32 restage in f1c region (8 x 4KB exact),
// + x2 residual (bf16) -> fp32 out, coalesced float4 stores.
__global__ __launch_bounds__(512, 2) void ffn_fused(const bf16* __restrict__ hf,
                                                    const bf16* __restrict__ W1,
                                                    const bf16* __restrict__ W2,
                                                    const bf16* __restrict__ x2,
                                                    float* __restrict__ out) {
  extern __shared__ __align__(16) bf16 smem[];        // 81920 B
  const int tid = threadIdx.x;
  const int wid = tid >> 6, lane = tid & 63;
  const int l15 = lane & 15, quad = lane >> 4;
  const int tM = blockIdx.x * 128;
  const int wM  = (wid >> 2) * 64;                    // row band (both GEMMs)
  const int wN1 = (wid & 3) * 32;                     // GEMM1 f1-col band
  const int wN2 = (wid & 3) * 128;                    // GEMM2 out-col band
  const int kq = (quad ^ ((l15 >> 1) & 3)) * 8;       // T2 slot (stage bufs)
  bf16* f1c = smem + 24576;                           // 128x128, slot-swizzled

  const int srow = tid >> 2;
  const int scol = ((tid & 3) ^ ((tid >> 3) & 3)) * 8;

  auto stage1 = [&](int cc, int t, int p) {           // 2 gload_lds / thread
    const int k0 = t * 32;
    bf16* dH = smem + p * 8192;
    bf16* dW = dH + 4096;
    gload_lds16(hf + (size_t)(tM + srow) * DIM + k0 + scol, &dH[tid * 8]);
    gload_lds16(W1 + (size_t)(cc * 128 + srow) * DIM + k0 + scol, &dW[tid * 8]);
  };

  f32x4 acc2[4][8];
  const f32x4 z = {0.f, 0.f, 0.f, 0.f};
#pragma unroll
  for (int i = 0; i < 4; ++i)
#pragma unroll
    for (int j = 0; j < 8; ++j) acc2[i][j] = z;

  // prologue for chunk 0
  stage1(0, 0, 0);
  stage1(0, 1, 1);
  __builtin_amdgcn_sched_barrier(0);
  asm volatile("s_waitcnt vmcnt(2)" ::: "memory");
  __builtin_amdgcn_s_barrier();
  __builtin_amdgcn_sched_barrier(0);

  for (int c = 0; c < 16; ++c) {
    // ---- GEMM1: f1 chunk, K = 512 (16 steps) ----
    f32x4 acc1[4][2];
#pragma unroll
    for (int i = 0; i < 4; ++i) { acc1[i][0] = z; acc1[i][1] = z; }
    int cur = 0;
    for (int t = 0; t < 16; ++t) {
      if (t + 2 < 16) {
        int nx = cur + 2; if (nx >= 3) nx -= 3;
        stage1(c, t + 2, nx);
      }
      const bf16* Hs = smem + cur * 8192;
      const bf16* Ws = Hs + 4096;
      bf16x8 aF[4], bF[2];
#pragma unroll
      for (int i = 0; i < 4; ++i) aF[i] = *(const bf16x8*)&Hs[(wM + i * 16 + l15) * 32 + kq];
#pragma unroll
      for (int j = 0; j < 2; ++j) bF[j] = *(const bf16x8*)&Ws[(wN1 + j * 16 + l15) * 32 + kq];
#pragma unroll
      for (int i = 0; i < 4; ++i)
#pragma unroll
        for (int j = 0; j < 2; ++j) acc1[i][j] = mfma16(aF[i], bF[j], acc1[i][j]);
      if (t < 15) {
        __builtin_amdgcn_sched_barrier(0);
        if (t + 2 < 16) asm volatile("s_waitcnt vmcnt(2)" ::: "memory");
        else            asm volatile("s_waitcnt vmcnt(0)" ::: "memory");
        __builtin_amdgcn_s_barrier();
        __builtin_amdgcn_sched_barrier(0);
      }
      ++cur; if (cur == 3) cur = 0;
    }
    // ---- barrier A: all waves done with GEMM1 bufs and prior f1c reads ----
    __builtin_amdgcn_sched_barrier(0);
    __builtin_amdgcn_s_barrier();
    __builtin_amdgcn_sched_barrier(0);
    // ---- GELU -> f1c (slot-swizzled) ----
#pragma unroll
    for (int i = 0; i < 4; ++i)
#pragma unroll
      for (int j = 0; j < 2; ++j)
#pragma unroll
        for (int r = 0; r < 4; ++r) {
          const int rowW = wM + i * 16 + quad * 4 + r;
          const int colW = wN1 + j * 16 + l15;
          f1c[rowW * 128 + ((((colW >> 3) ^ (rowW & 7))) << 3) + (colW & 7)] =
              (bf16)fast_gelu(acc1[i][j][r]);
        }
    // issue next chunk's first stages now; they land under GEMM2
    if (c < 15) { stage1(c + 1, 0, 0); stage1(c + 1, 1, 1); }
    asm volatile("s_waitcnt lgkmcnt(0)" ::: "memory");
    __builtin_amdgcn_sched_barrier(0);
    __builtin_amdgcn_s_barrier();                     // barrier B: f1c visible
    __builtin_amdgcn_sched_barrier(0);
    // ---- GEMM2: acc2 += f1c @ W2[:, c-chunk]^T (4 steps) ----
    const bf16* w2c = W2 + c * 128;
#pragma unroll
    for (int kk = 0; kk < 4; ++kk) {
      bf16x8 a2[4], b2[8];
#pragma unroll
      for (int i = 0; i < 4; ++i) {
        const int row = wM + i * 16 + l15;
        a2[i] = *(const bf16x8*)&f1c[row * 128 + (((kk * 4 + quad) ^ (l15 & 7)) << 3)];
      }
#pragma unroll
      for (int j = 0; j < 8; ++j)
        b2[j] = *(const bf16x8*)(w2c + (size_t)(wN2 + j * 16 + l15) * 2048 + kk * 32 + quad * 8);
#pragma unroll
      for (int i = 0; i < 4; ++i)
#pragma unroll
        for (int j = 0; j < 8; ++j) acc2[i][j] = mfma16(a2[i], b2[j], acc2[i][j]);
    }
    if (c < 15) {
      __builtin_amdgcn_sched_barrier(0);
      asm volatile("s_waitcnt vmcnt(2)" ::: "memory"); // next chunk t0 landed
      __builtin_amdgcn_s_barrier();                    // barrier C
      __builtin_amdgcn_sched_barrier(0);
    }
  }

  // ---- epilogue: + x2 residual -> fp32 out (per-wave restage in f1c) ----
  __builtin_amdgcn_sched_barrier(0);
  __builtin_amdgcn_s_barrier();                        // f1c reads all done
  __builtin_amdgcn_sched_barrier(0);
  float* obf = (float*)f1c + wid * 1024;               // 16x64 f32 = 4 KiB/wave
  const int ch = lane & 7;
#pragma unroll
  for (int i = 0; i < 4; ++i)
#pragma unroll
    for (int jh = 0; jh < 2; ++jh) {
#pragma unroll
      for (int j2 = 0; j2 < 4; ++j2)
#pragma unroll
        for (int r = 0; r < 4; ++r)
          obf[(quad * 4 + r) * 64 + j2 * 16 + l15] = acc2[i][jh * 4 + j2][r];
#pragma unroll
      for (int t = 0; t < 2; ++t) {
        const int rr = t * 8 + (lane >> 3);
        const int rowg = tM + wM + i * 16 + rr;
        const size_t idx = (size_t)rowg * DIM + wN2 + jh * 64 + ch * 8;
        const float4* rp = (const float4*)&obf[rr * 64 + ch * 8];
        float4 a = rp[0], b = rp[1];
        float f[8] = {a.x, a.y, a.z, a.w, b.x, b.y, b.z, b.w};
        bf16x8 xv = *(const bf16x8*)(x2 + idx);
#pragma unroll
        for (int u = 0; u < 8; ++u) f[u] += (float)xv[u];
        float4 o0 = {f[0], f[1], f[2], f[3]}, o1 = {f[4], f[5], f[6], f[7]};
        ((float4*)(out + idx))[0] = o0;
        ((float4*)(out + idx))[1] = o1;
      }
    }
}

// ---------------- windowed attention: one block per (b,h,window) ----------------
__global__ __launch_bounds__(256, 3) void attn_kernel(const bf16* __restrict__ q,
                                                      const bf16* __restrict__ k,
                                                      const bf16* __restrict__ v,
                                                      bf16* __restrict__ ao) {
  __shared__ __align__(16) bf16 kv[256 * 72];       // K [tok][72]; later V^T [d][264]
  __shared__ __align__(16) bf16 pbuf[4][16 * 136];  // per-wave half-P / O tile
  const int w = blockIdx.x, h = blockIdx.y, b = blockIdx.z;
  const int tid = threadIdx.x;
  const int wv = tid >> 6, lane = tid & 63;
  const int l15 = lane & 15, quad = lane >> 4;
  const size_t bh = (size_t)b * HEADS + h;
  const bf16* qb = q + bh * SEQ * DH;
  const bf16* kb = k + bh * SEQ * DH;
  const bf16* vb = v + bh * SEQ * DH;
  const int t0 = (w - 1) * WIN;                     // tile token range [t0, t0+256)

#pragma unroll
  for (int it = 0; it < 8; ++it) {
    const int c = it * 256 + tid;
    const int tok = c >> 3, ch = c & 7;
    int gt = t0 + tok; gt = gt < 0 ? 0 : gt;
    *(bf16x8*)&kv[tok * 72 + ch * 8] = *(const bf16x8*)(kb + (size_t)gt * DH + ch * 8);
  }
  bf16x8 aQ[2][2];
#pragma unroll
  for (int qt = 0; qt < 2; ++qt) {
    const int qtok = w * WIN + wv * 32 + qt * 16 + l15;
#pragma unroll
    for (int ks = 0; ks < 2; ++ks)
      aQ[qt][ks] = *(const bf16x8*)(qb + (size_t)qtok * DH + ks * 32 + quad * 8);
  }
  int gtv = t0 + tid; gtv = gtv < 0 ? 0 : gtv;
  bf16x8 vld[8];
#pragma unroll
  for (int dg = 0; dg < 8; ++dg)
    vld[dg] = *(const bf16x8*)(vb + (size_t)gtv * DH + dg * 8);
  __syncthreads();

  bf16x8 aP[2][8];
#pragma unroll
  for (int qt = 0; qt < 2; ++qt) {
    f32x4 sreg[16];
#pragma unroll
    for (int nt = 0; nt < 16; ++nt) {
      f32x4 a = {0.f, 0.f, 0.f, 0.f};
#pragma unroll
      for (int ks = 0; ks < 2; ++ks) {
        bf16x8 bK = *(const bf16x8*)&kv[(nt * 16 + l15) * 72 + ks * 32 + quad * 8];
        a = mfma16(aQ[qt][ks], bK, a);
      }
      sreg[nt] = a;
    }
    const int qlb = wv * 32 + qt * 16 + quad * 4;
    float rinv[4];
#pragma unroll
    for (int r = 0; r < 4; ++r) {
      const int ql = qlb + r;
      float sum = 0.f;
#pragma unroll
      for (int nt = 0; nt < 16; ++nt) {
        const int j = nt * 16 + l15;
        const bool valid = (nt < 8) ? (w > 0) : (ql >= j - WIN);
        const float p = valid ? __expf(sreg[nt][r]) : 0.0f;   // no max-sub: |s|<=8
        sreg[nt][r] = p;
        sum += p;
      }
#pragma unroll
      for (int m = 8; m; m >>= 1) sum += __shfl_xor(sum, m);
      rinv[r] = 1.0f / sum;
    }
#pragma unroll
    for (int half = 0; half < 2; ++half) {
#pragma unroll
      for (int ntw = 0; ntw < 8; ++ntw)
#pragma unroll
        for (int r = 0; r < 4; ++r)
          pbuf[wv][(quad * 4 + r) * 136 + ntw * 16 + l15] =
              (bf16)(sreg[half * 8 + ntw][r] * rinv[r]);
#pragma unroll
      for (int kk = 0; kk < 4; ++kk)
        aP[qt][half * 4 + kk] = *(const bf16x8*)&pbuf[wv][l15 * 136 + kk * 32 + quad * 8];
    }
  }
  __syncthreads();

#pragma unroll
  for (int dg = 0; dg < 8; ++dg)
#pragma unroll
    for (int i = 0; i < 8; ++i)
      kv[(dg * 8 + i) * 264 + tid] = vld[dg][i];
  __syncthreads();

#pragma unroll
  for (int qt = 0; qt < 2; ++qt) {
#pragma unroll
    for (int dt = 0; dt < 4; ++dt) {
      f32x4 o = {0.f, 0.f, 0.f, 0.f};
#pragma unroll
      for (int ks2 = 0; ks2 < 8; ++ks2) {
        bf16x8 bV = *(const bf16x8*)&kv[(dt * 16 + l15) * 264 + ks2 * 32 + quad * 8];
        o = mfma16(aP[qt][ks2], bV, o);
      }
#pragma unroll
      for (int r = 0; r < 4; ++r)
        pbuf[wv][(quad * 4 + r) * 136 + dt * 16 + l15] = (bf16)o[r];
    }
#pragma unroll
    for (int t = 0; t < 2; ++t) {
      const int rr = t * 8 + (lane >> 3), ch = lane & 7;
      bf16x8 ov = *(const bf16x8*)&pbuf[wv][rr * 136 + ch * 8];
      const int tok = w * WIN + wv * 32 + qt * 16 + rr;
      *(bf16x8*)(ao + ((size_t)b * SEQ + tok) * DIM + h * DH + ch * 8) = ov;
    }
  }
}

extern "C" void kernel_launch(void* const* d_in, const int* in_sizes, int n_in,
                              void* d_out, int out_size, void* d_ws, size_t ws_size,
                              hipStream_t stream) {
  (void)in_sizes; (void)n_in; (void)out_size; (void)ws_size;
  float* out = (float*)d_out;                      // fp32 output per reference dtype
  bf16* cano = (bf16*)d_ws;
  const unsigned short* probe = (const unsigned short*)d_in[2];

  SrcPtrs sp;
  for (int i = 0; i < 12; ++i) sp.p[i] = d_in[i];

  bf16* slot0 = cano + P_EL;             // h -> ao -> hf
  bf16* slot1 = cano + P_EL + R_EL;      // q -> x2
  bf16* slot2 = cano + P_EL + 2 * R_EL;  // k
  bf16* slot3 = cano + P_EL + 3 * R_EL;  // v (natural head-major layout)

  const bf16* qsc  = cano + C_SM + 0;
  const bf16* ksc  = cano + C_SM + 64;
  const bf16* bout = cano + C_SM + 128;
  const bf16* l1g  = cano + C_SM + 640;
  const bf16* l1b  = cano + C_SM + 1152;
  const bf16* lfg  = cano + C_SM + 1664;
  const bf16* lfb  = cano + C_SM + 2176;

  constexpr int LDSB = 3 * 12288 * 2;    // 73728 B dynamic LDS for gemm_bt
  constexpr int LDSF = 81920;            // dynamic LDS for ffn_fused
  static bool attr_done = false;
  if (!attr_done) {
    hipFuncSetAttribute((const void*)gemm_bt<0>, hipFuncAttributeMaxDynamicSharedMemorySize, LDSB);
    hipFuncSetAttribute((const void*)gemm_bt<1>, hipFuncAttributeMaxDynamicSharedMemorySize, LDSB);
    hipFuncSetAttribute((const void*)ffn_fused, hipFuncAttributeMaxDynamicSharedMemorySize, LDSF);
    attr_done = true;
  }

  ingest_kernel<<<1538, 256, 0, stream>>>(sp, cano);
  ln_kernel<<<TOK / 4, 256, 0, stream>>>(d_in[0], l1g, l1b, slot0, probe, 1);
  gemm_bt<0><<<16 * 96, 512, LDSB, stream>>>(slot0, cano + C_QKV, slot1, slot2, slot3,
                                             nullptr, nullptr, qsc, ksc, probe,
                                             DIM, DIM, 0, 12);
  attn_kernel<<<dim3(NW, HEADS, BATCH), 256, 0, stream>>>(slot1, slot2, slot3, slot0);
  gemm_bt<1><<<16 * 32, 512, LDSB, stream>>>(slot0, cano + C_WOUT, slot1, nullptr, nullptr,
                                             nullptr, d_in[0], nullptr, bout, probe,
                                             DIM, DIM, 0, 4);
  ln_kernel<<<TOK / 4, 256, 0, stream>>>(slot1, lfg, lfb, slot0, probe, 0);
  ffn_fused<<<TOK / 128, 512, LDSF, stream>>>(slot0, cano + C_WF1, cano + C_WF2,
                                              slot1, out);
}

// Round 8
// 499.209 us; speedup vs baseline: 1.1070x; 1.1070x over previous
//
#include <hip/hip_runtime.h>
#include <cstdint>
#include <cstddef>

typedef __bf16 bf16;
typedef __bf16 bf16x8 __attribute__((ext_vector_type(8)));
typedef float f32x4 __attribute__((ext_vector_type(4)));

#define DEV static __device__ __forceinline__

constexpr int BATCH = 8;
constexpr int SEQ = 4096;
constexpr int DIM = 512;
constexpr int HEADS = 8;
constexpr int DH = 64;
constexpr int WIN = 128;
constexpr int NW = SEQ / WIN;        // 32
constexpr int TOK = BATCH * SEQ;     // 32768
constexpr float EPS = 1e-5f;

// canonical bf16 weights in workspace (element offsets)
constexpr size_t R_EL   = (size_t)TOK * DIM;            // 16,777,216
constexpr size_t C_QKV  = 0;                             // 786432
constexpr size_t C_WOUT = 786432;                        // 262144
constexpr size_t C_WF1  = 1048576;                       // 1048576
constexpr size_t C_WF2  = 2097152;                       // 1048576
constexpr size_t C_SM   = 3145728;                       // 2688 smalls
// smalls: qsc 0, ksc 64, bout 128, l1g 640, l1b 1152, lfg 1664, lfb 2176
constexpr size_t P_EL   = 3148416;                       // slot base (%8==0)

DEV void gload_lds16(const void* g, void* l) {
  __builtin_amdgcn_global_load_lds((__attribute__((address_space(1))) void*)g,
                                   (__attribute__((address_space(3))) void*)l,
                                   16, 0, 0);
}

DEV f32x4 mfma16(bf16x8 a, bf16x8 b, f32x4 c) {
  return __builtin_amdgcn_mfma_f32_16x16x32_bf16(a, b, c, 0, 0, 0);
}

// Branchless exact-GELU via Abramowitz-Stegun 7.1.26 erf approximation.
// |erf error| <= 1.5e-7 (far below bf16 output rounding). ~16 cheap VALU ops,
// no divergence -- vs library erff's two-path implementation.
DEV float fast_gelu(float v) {
  const float z = fabsf(v) * 0.7071067811865476f;
  const float t = __builtin_amdgcn_rcpf(1.0f + 0.3275911f * z);
  const float p = t * (0.254829592f +
                  t * (-0.284496736f +
                  t * (1.421413741f +
                  t * (-1.453152027f +
                  t * 1.061405429f))));
  const float e = __expf(-z * z);
  const float erfa = 1.0f - p * e;               // erf(|v|/sqrt2)
  const float cdf = 0.5f + copysignf(0.5f * erfa, v);
  return v * cdf;
}

// ---------------- ingest: dtype-probe + convert weight inputs to bf16 ----------
struct SrcPtrs { const void* p[12]; };

DEV void copy8(const void* src, long si, bf16* dst, bool f32) {
  if (f32) {
    const float4* s = (const float4*)((const float*)src + si);
    float4 a = s[0], b = s[1];
    bf16x8 o;
    o[0] = (bf16)a.x; o[1] = (bf16)a.y; o[2] = (bf16)a.z; o[3] = (bf16)a.w;
    o[4] = (bf16)b.x; o[5] = (bf16)b.y; o[6] = (bf16)b.z; o[7] = (bf16)b.w;
    *(bf16x8*)dst = o;
  } else {
    *(bf16x8*)dst = *(const bf16x8*)((const bf16*)src + si);
  }
}

__global__ __launch_bounds__(256) void ingest_kernel(SrcPtrs sp, bf16* cano) {
  const bool f32 = (((const unsigned short*)sp.p[2])[0] == 0);
  const long e = (long)threadIdx.x * 8;
  int b = blockIdx.x;
  if (b < 384)  { long o = (long)b * 2048 + e; copy8(sp.p[1], o, cano + C_QKV + o, f32); return; }
  b -= 384;
  if (b < 128)  { long o = (long)b * 2048 + e; copy8(sp.p[4], o, cano + C_WOUT + o, f32); return; }
  b -= 128;
  if (b < 512)  { long o = (long)b * 2048 + e; copy8(sp.p[10], o, cano + C_WF1 + o, f32); return; }
  b -= 512;
  if (b < 512)  { long o = (long)b * 2048 + e; copy8(sp.p[11], o, cano + C_WF2 + o, f32); return; }
  b -= 512;
  const long o = (long)b * 2048 + e;
  if (o >= 2688) return;
  const void* src; long si;
  if      (o < 64)   { src = sp.p[2]; si = o; }
  else if (o < 128)  { src = sp.p[3]; si = o - 64; }
  else if (o < 640)  { src = sp.p[5]; si = o - 128; }
  else if (o < 1152) { src = sp.p[6]; si = o - 640; }
  else if (o < 1664) { src = sp.p[7]; si = o - 1152; }
  else if (o < 2176) { src = sp.p[8]; si = o - 1664; }
  else               { src = sp.p[9]; si = o - 2176; }
  copy8(src, si, cano + C_SM + o, f32);
}

// ---------------- LayerNorm: one wave per 512-dim token ----------------
__global__ __launch_bounds__(256) void ln_kernel(const void* __restrict__ in,
                                                 const bf16* __restrict__ gg,
                                                 const bf16* __restrict__ bb,
                                                 bf16* __restrict__ out,
                                                 const unsigned short* __restrict__ probe,
                                                 int raw) {
  const int wave = threadIdx.x >> 6, lane = threadIdx.x & 63;
  const int row = blockIdx.x * 4 + wave;
  const size_t base = (size_t)row * DIM + lane * 8;
  float f[8];
  if (raw && probe[0] == 0) {
    const float4* p = (const float4*)((const float*)in + base);
    float4 a = p[0], bq = p[1];
    f[0] = a.x; f[1] = a.y; f[2] = a.z; f[3] = a.w;
    f[4] = bq.x; f[5] = bq.y; f[6] = bq.z; f[7] = bq.w;
  } else {
    bf16x8 v = *(const bf16x8*)((const bf16*)in + base);
#pragma unroll
    for (int i = 0; i < 8; ++i) f[i] = (float)v[i];
  }
  float s = 0.f, sq = 0.f;
#pragma unroll
  for (int i = 0; i < 8; ++i) { s += f[i]; sq += f[i] * f[i]; }
#pragma unroll
  for (int m = 32; m; m >>= 1) { s += __shfl_xor(s, m); sq += __shfl_xor(sq, m); }
  const float mean = s * (1.0f / DIM);
  const float var = fmaxf(sq * (1.0f / DIM) - mean * mean, 0.0f);
  const float rs = rsqrtf(var + EPS);
  bf16x8 gv = *(const bf16x8*)(gg + lane * 8);
  bf16x8 bv = *(const bf16x8*)(bb + lane * 8);
  bf16x8 o;
#pragma unroll
  for (int i = 0; i < 8; ++i) o[i] = (bf16)((f[i] - mean) * rs * (float)gv[i] + (float)bv[i]);
  *(bf16x8*)((bf16*)out + base) = o;
}

// ---------------- GEMM: C = A(MxK) @ Bw(N x K, row-stride bstride)^T ----------------
// 256x128 tile, 8 waves (4M x 2N), 3-buffer depth-2 counted-vmcnt pipeline +
// T2 LDS swizzle (proven R6 structure).  Used for QKV (MODE 0) and WOUT
// (MODE 1); the FF pair uses gemm_ff below (8x4 fragment reuse).
template <int MODE>
__global__ __launch_bounds__(512) void gemm_bt(const bf16* __restrict__ A,
                                               const bf16* __restrict__ Bw,
                                               bf16* __restrict__ O0, bf16* __restrict__ O1,
                                               bf16* __restrict__ O2,
                                               float* __restrict__ Of,
                                               const void* __restrict__ Xraw,
                                               const bf16* __restrict__ Xb,
                                               const bf16* __restrict__ bias,
                                               const unsigned short* __restrict__ probe,
                                               int K, int bstride, int ostride, int gx) {
  extern __shared__ __align__(16) bf16 smem[];        // 3 * 12288 elems = 72 KiB
  const int tid = threadIdx.x;
  const int wid = tid >> 6, lane = tid & 63;
  const int l15 = lane & 15, quad = lane >> 4;
  const int id = blockIdx.x;
  const int per = gx * 8;
  const int tM = ((id / per) * 8 + (id & 7)) * 256;
  const int tN = ((id % per) >> 3) * 128;
  const int wM = (wid >> 1) * 64, wN = (wid & 1) * 64;
  const int kq = (quad ^ ((l15 >> 1) & 3)) * 8;
  f32x4 acc[4][4];
  const f32x4 z = {0.f, 0.f, 0.f, 0.f};
#pragma unroll
  for (int i = 0; i < 4; ++i)
#pragma unroll
    for (int j = 0; j < 4; ++j) acc[i][j] = z;

  const int cA0 = tid,       rA0 = cA0 >> 2, sA0 = (((cA0 & 3) ^ ((cA0 >> 3) & 3)) * 8);
  const int cA1 = tid + 512, rA1 = cA1 >> 2, sA1 = (((cA1 & 3) ^ ((cA1 >> 3) & 3)) * 8);
  const int cB0 = tid,       rB0 = cB0 >> 2, sB0 = sA0;

  auto stage = [&](int t, int p) {
    const int k0 = t * 32;
    bf16* dA = smem + p * 12288;
    bf16* dB = dA + 8192;
    gload_lds16(A  + (size_t)(tM + rA0) * K       + k0 + sA0, &dA[cA0 * 8]);
    gload_lds16(A  + (size_t)(tM + rA1) * K       + k0 + sA1, &dA[cA1 * 8]);
    gload_lds16(Bw + (size_t)(tN + rB0) * bstride + k0 + sB0, &dB[cB0 * 8]);
  };

  const int nt = K >> 5;
  stage(0, 0);
  stage(1, 1);
  __builtin_amdgcn_sched_barrier(0);
  asm volatile("s_waitcnt vmcnt(3)" ::: "memory");
  __builtin_amdgcn_s_barrier();
  __builtin_amdgcn_sched_barrier(0);

  int cur = 0;
  for (int t = 0; t < nt; ++t) {
    if (t + 2 < nt) {
      int nx = cur + 2; if (nx >= 3) nx -= 3;
      stage(t + 2, nx);
    }
    const bf16* As = smem + cur * 12288;
    const bf16* Bs = As + 8192;
    bf16x8 aF[4], bF[4];
#pragma unroll
    for (int i = 0; i < 4; ++i) aF[i] = *(const bf16x8*)&As[(wM + i * 16 + l15) * 32 + kq];
#pragma unroll
    for (int j = 0; j < 4; ++j) bF[j] = *(const bf16x8*)&Bs[(wN + j * 16 + l15) * 32 + kq];
#pragma unroll
    for (int i = 0; i < 4; ++i)
#pragma unroll
      for (int j = 0; j < 4; ++j) acc[i][j] = mfma16(aF[i], bF[j], acc[i][j]);
    if (t < nt - 1) {
      __builtin_amdgcn_sched_barrier(0);
      if (t + 2 < nt) asm volatile("s_waitcnt vmcnt(3)" ::: "memory");
      else            asm volatile("s_waitcnt vmcnt(0)" ::: "memory");
      __builtin_amdgcn_s_barrier();
      __builtin_amdgcn_sched_barrier(0);
    }
    ++cur; if (cur == 3) cur = 0;
  }
  const int q0 = nt % 3;
  bf16* eb = smem + q0 * 12288;

  if constexpr (MODE == 0) {
    bf16* ob = eb + wid * 1152;
    const int colbase = tN + wN;
    const int which = colbase >> 9;
    const int head = (colbase >> 6) & 7;
    bf16* dst = which == 0 ? O0 : (which == 1 ? O1 : O2);
    const int ch = lane & 7;
    float scv[8], invf[8];
    if (which < 2) {
      const bf16* sc = which ? bias : Xb;             // ksc : qsc
      bf16x8 s8 = *(const bf16x8*)(sc + ch * 8);
#pragma unroll
      for (int u = 0; u < 8; ++u) {
        scv[u] = (float)s8[u] * (which == 0 ? 8.0f : 1.0f);   // fold QK_SCALE into q
        invf[u] = exp2f(-(float)((ch & 3) * 8 + u) * (13.287712379549449f / 32.0f));
      }
    }
#pragma unroll
    for (int i = 0; i < 4; ++i) {
#pragma unroll
      for (int j = 0; j < 4; ++j)
#pragma unroll
        for (int r = 0; r < 4; ++r)
          ob[(quad * 4 + r) * 72 + j * 16 + l15] = (bf16)acc[i][j][r];
#pragma unroll
      for (int t = 0; t < 2; ++t) {
        const int rr = t * 8 + (lane >> 3);
        const int rowg = tM + wM + i * 16 + rr;
        bf16x8 ov = *(const bf16x8*)&ob[rr * 72 + ch * 8];
        float f[8];
#pragma unroll
        for (int u = 0; u < 8; ++u) f[u] = (float)ov[u];
        if (which < 2) {
          float ss = 0.f;
#pragma unroll
          for (int u = 0; u < 8; ++u) ss += f[u] * f[u];
          ss += __shfl_xor(ss, 1); ss += __shfl_xor(ss, 2); ss += __shfl_xor(ss, 4);
          const float rs = 1.0f / fmaxf(sqrtf(ss), 1e-12f);
#pragma unroll
          for (int u = 0; u < 8; ++u) f[u] *= rs * scv[u];
          float pf[8];
#pragma unroll
          for (int u = 0; u < 8; ++u) pf[u] = __shfl_xor(f[u], 4);
          const float pos = (float)(rowg & (SEQ - 1));
#pragma unroll
          for (int u = 0; u < 8; ++u) {
            float sn, cs;
            __sincosf(pos * invf[u], &sn, &cs);
            const float rot = (ch < 4) ? -pf[u] : pf[u];
            f[u] = f[u] * cs + rot * sn;
          }
        }
        bf16x8 o8;
#pragma unroll
        for (int u = 0; u < 8; ++u) o8[u] = (bf16)f[u];
        const int bb = rowg >> 12, n = rowg & (SEQ - 1);
        *(bf16x8*)(dst + ((size_t)(bb * HEADS + head) * SEQ + n) * DH + ch * 8) = o8;
      }
    }
    return;
  }

  if constexpr (MODE == 1) {
    bf16* ob = eb + wid * 1152;
    const int ch = lane & 7;
    bf16x8 bias8 = *(const bf16x8*)(bias + tN + wN + ch * 8);
    const bool xf32 = (probe[0] == 0);
#pragma unroll
    for (int i = 0; i < 4; ++i) {
#pragma unroll
      for (int j = 0; j < 4; ++j)
#pragma unroll
        for (int r = 0; r < 4; ++r)
          ob[(quad * 4 + r) * 72 + j * 16 + l15] = (bf16)acc[i][j][r];
#pragma unroll
      for (int t = 0; t < 2; ++t) {
        const int rr = t * 8 + (lane >> 3);
        const int rowg = tM + wM + i * 16 + rr;
        bf16x8 ov = *(const bf16x8*)&ob[rr * 72 + ch * 8];
        bf16x8 o8;
        const size_t idx = (size_t)rowg * DIM + tN + wN + ch * 8;
        float xr[8];
        if (xf32) {
          const float4* xp = (const float4*)((const float*)Xraw + idx);
          float4 a = xp[0], bq = xp[1];
          xr[0] = a.x; xr[1] = a.y; xr[2] = a.z; xr[3] = a.w;
          xr[4] = bq.x; xr[5] = bq.y; xr[6] = bq.z; xr[7] = bq.w;
        } else {
          bf16x8 xv = *(const bf16x8*)((const bf16*)Xraw + idx);
#pragma unroll
          for (int u = 0; u < 8; ++u) xr[u] = (float)xv[u];
        }
#pragma unroll
        for (int u = 0; u < 8; ++u) o8[u] = (bf16)((float)ov[u] + xr[u] + (float)bias8[u]);
        *(bf16x8*)(O0 + idx) = o8;
      }
    }
    return;
  }
}

// ---------------- FF GEMM: 256x256 tile, per-wave 128x64 (8x4 fragments) ------
// Same 3-buffer depth-2 counted-vmcnt schedule + T2 swizzle as gemm_bt, but
// 8x4 fragment reuse: 12 ds_read_b128 feed 32 MFMA (1B LDS per 42.7 FLOP vs
// 1/32 for the 4x4 grid) -- relieves the LDS pipe that caps gemm_bt's
// MfmaUtil at ~30% (R6 analysis; matches m201's 8x4 choice at 62% MfmaUtil).
// 8 waves as 2M x 4N: wm=wid>>2 (row band *128), wn=wid&3 (col band *64).
// Buffer = A 256x32 + B 256x32 = 32 KiB; x3 = 96 KiB -> 1 block/CU, 8 waves.
// Stage = 4 uniform loads/thread; steady tails vmcnt(4), last vmcnt(0).
// Epilogues barrier-free: q0 = nt%3 never read in final iter; bf16 restage
// 8x1152 el = 18 KiB <= 32 KiB; f32 restage 8x1024 f32 = 32 KiB exactly.
// MODE 2: fast exact gelu -> O0 bf16 (stride ostride)
// MODE 3: + Xb residual -> Of fp32 (stride DIM)
// MODE 4: + Of readback -> Of fp32 (stride DIM)
template <int MODE>
__global__ __launch_bounds__(512, 2) void gemm_ff(const bf16* __restrict__ A,
                                                  const bf16* __restrict__ Bw,
                                                  bf16* __restrict__ O0,
                                                  float* __restrict__ Of,
                                                  const bf16* __restrict__ Xb,
                                                  int K, int bstride, int ostride, int gx) {
  extern __shared__ __align__(16) bf16 smem[];        // 3 * 16384 elems = 96 KiB
  const int tid = threadIdx.x;
  const int wid = tid >> 6, lane = tid & 63;
  const int l15 = lane & 15, quad = lane >> 4;
  const int id = blockIdx.x;
  const int per = gx * 8;
  const int tM = ((id / per) * 8 + (id & 7)) * 256;
  const int tN = ((id % per) >> 3) * 256;
  const int wm = (wid >> 2) * 128, wn = (wid & 3) * 64;
  const int kq = (quad ^ ((l15 >> 1) & 3)) * 8;
  f32x4 acc[8][4];
  const f32x4 z = {0.f, 0.f, 0.f, 0.f};
#pragma unroll
  for (int i = 0; i < 8; ++i)
#pragma unroll
    for (int j = 0; j < 4; ++j) acc[i][j] = z;

  const int c0 = tid,       r0 = c0 >> 2, s0 = (((c0 & 3) ^ ((c0 >> 3) & 3)) * 8);
  const int c1 = tid + 512, r1 = c1 >> 2, s1 = (((c1 & 3) ^ ((c1 >> 3) & 3)) * 8);

  auto stage = [&](int t, int p) {                    // 4 gload_lds per thread
    const int k0 = t * 32;
    bf16* dA = smem + p * 16384;
    bf16* dB = dA + 8192;
    gload_lds16(A  + (size_t)(tM + r0) * K       + k0 + s0, &dA[c0 * 8]);
    gload_lds16(A  + (size_t)(tM + r1) * K       + k0 + s1, &dA[c1 * 8]);
    gload_lds16(Bw + (size_t)(tN + r0) * bstride + k0 + s0, &dB[c0 * 8]);
    gload_lds16(Bw + (size_t)(tN + r1) * bstride + k0 + s1, &dB[c1 * 8]);
  };

  const int nt = K >> 5;
  stage(0, 0);
  stage(1, 1);
  __builtin_amdgcn_sched_barrier(0);
  asm volatile("s_waitcnt vmcnt(4)" ::: "memory");    // tile0 landed (tile1 in flight)
  __builtin_amdgcn_s_barrier();
  __builtin_amdgcn_sched_barrier(0);

  int cur = 0;
  for (int t = 0; t < nt; ++t) {
    if (t + 2 < nt) {
      int nx = cur + 2; if (nx >= 3) nx -= 3;
      stage(t + 2, nx);
    }
    const bf16* As = smem + cur * 16384;
    const bf16* Bs = As + 8192;
    bf16x8 aF[8], bF[4];
#pragma unroll
    for (int i = 0; i < 8; ++i) aF[i] = *(const bf16x8*)&As[(wm + i * 16 + l15) * 32 + kq];
#pragma unroll
    for (int j = 0; j < 4; ++j) bF[j] = *(const bf16x8*)&Bs[(wn + j * 16 + l15) * 32 + kq];
#pragma unroll
    for (int i = 0; i < 8; ++i)
#pragma unroll
      for (int j = 0; j < 4; ++j) acc[i][j] = mfma16(aF[i], bF[j], acc[i][j]);
    if (t < nt - 1) {
      __builtin_amdgcn_sched_barrier(0);
      if (t + 2 < nt) asm volatile("s_waitcnt vmcnt(4)" ::: "memory");
      else            asm volatile("s_waitcnt vmcnt(0)" ::: "memory");
      __builtin_amdgcn_s_barrier();
      __builtin_amdgcn_sched_barrier(0);
    }
    ++cur; if (cur == 3) cur = 0;
  }
  const int q0 = nt % 3;                              // never read in final iter
  bf16* eb = smem + q0 * 16384;
  const int ch = lane & 7;

  if constexpr (MODE == 2) {
    bf16* ob = eb + wid * 1152;                       // 16 x 72
#pragma unroll
    for (int i = 0; i < 8; ++i) {
#pragma unroll
      for (int j = 0; j < 4; ++j)
#pragma unroll
        for (int r = 0; r < 4; ++r)
          ob[(quad * 4 + r) * 72 + j * 16 + l15] = (bf16)acc[i][j][r];
#pragma unroll
      for (int t = 0; t < 2; ++t) {
        const int rr = t * 8 + (lane >> 3);
        const int rowg = tM + wm + i * 16 + rr;
        bf16x8 ov = *(const bf16x8*)&ob[rr * 72 + ch * 8];
        bf16x8 o8;
#pragma unroll
        for (int u = 0; u < 8; ++u) o8[u] = (bf16)fast_gelu((float)ov[u]);
        *(bf16x8*)(O0 + (size_t)rowg * ostride + tN + wn + ch * 8) = o8;
      }
    }
    return;
  }

  if constexpr (MODE == 3 || MODE == 4) {
    float* obf = (float*)eb + wid * 1024;             // 16 x 64 f32 = 4 KiB/wave
#pragma unroll
    for (int i = 0; i < 8; ++i) {
#pragma unroll
      for (int j = 0; j < 4; ++j)
#pragma unroll
        for (int r = 0; r < 4; ++r)
          obf[(quad * 4 + r) * 64 + j * 16 + l15] = acc[i][j][r];
#pragma unroll
      for (int t = 0; t < 2; ++t) {
        const int rr = t * 8 + (lane >> 3);
        const int rowg = tM + wm + i * 16 + rr;
        const size_t idx = (size_t)rowg * DIM + tN + wn + ch * 8;
        const float4* rp = (const float4*)&obf[rr * 64 + ch * 8];
        float4 a = rp[0], b = rp[1];
        float f[8] = {a.x, a.y, a.z, a.w, b.x, b.y, b.z, b.w};
        if constexpr (MODE == 3) {
          bf16x8 xv = *(const bf16x8*)(Xb + idx);
#pragma unroll
          for (int u = 0; u < 8; ++u) f[u] += (float)xv[u];
        } else {
          const float4* op = (const float4*)(Of + idx);
          float4 oa = op[0], ob4 = op[1];
          f[0] += oa.x; f[1] += oa.y; f[2] += oa.z; f[3] += oa.w;
          f[4] += ob4.x; f[5] += ob4.y; f[6] += ob4.z; f[7] += ob4.w;
        }
        float4 o0 = {f[0], f[1], f[2], f[3]}, o1 = {f[4], f[5], f[6], f[7]};
        ((float4*)(Of + idx))[0] = o0;
        ((float4*)(Of + idx))[1] = o1;
      }
    }
    return;
  }
}

// ---------------- windowed attention: one block per (b,h,window) ----------------
__global__ __launch_bounds__(256, 3) void attn_kernel(const bf16* __restrict__ q,
                                                      const bf16* __restrict__ k,
                                                      const bf16* __restrict__ v,
                                                      bf16* __restrict__ ao) {
  __shared__ __align__(16) bf16 kv[256 * 72];       // K [tok][72]; later V^T [d][264]
  __shared__ __align__(16) bf16 pbuf[4][16 * 136];  // per-wave half-P / O tile
  const int w = blockIdx.x, h = blockIdx.y, b = blockIdx.z;
  const int tid = threadIdx.x;
  const int wv = tid >> 6, lane = tid & 63;
  const int l15 = lane & 15, quad = lane >> 4;
  const size_t bh = (size_t)b * HEADS + h;
  const bf16* qb = q + bh * SEQ * DH;
  const bf16* kb = k + bh * SEQ * DH;
  const bf16* vb = v + bh * SEQ * DH;
  const int t0 = (w - 1) * WIN;                     // tile token range [t0, t0+256)

#pragma unroll
  for (int it = 0; it < 8; ++it) {
    const int c = it * 256 + tid;
    const int tok = c >> 3, ch = c & 7;
    int gt = t0 + tok; gt = gt < 0 ? 0 : gt;
    *(bf16x8*)&kv[tok * 72 + ch * 8] = *(const bf16x8*)(kb + (size_t)gt * DH + ch * 8);
  }
  bf16x8 aQ[2][2];
#pragma unroll
  for (int qt = 0; qt < 2; ++qt) {
    const int qtok = w * WIN + wv * 32 + qt * 16 + l15;
#pragma unroll
    for (int ks = 0; ks < 2; ++ks)
      aQ[qt][ks] = *(const bf16x8*)(qb + (size_t)qtok * DH + ks * 32 + quad * 8);
  }
  int gtv = t0 + tid; gtv = gtv < 0 ? 0 : gtv;
  bf16x8 vld[8];
#pragma unroll
  for (int dg = 0; dg < 8; ++dg)
    vld[dg] = *(const bf16x8*)(vb + (size_t)gtv * DH + dg * 8);
  __syncthreads();

  bf16x8 aP[2][8];
#pragma unroll
  for (int qt = 0; qt < 2; ++qt) {
    f32x4 sreg[16];
#pragma unroll
    for (int nt = 0; nt < 16; ++nt) {
      f32x4 a = {0.f, 0.f, 0.f, 0.f};
#pragma unroll
      for (int ks = 0; ks < 2; ++ks) {
        bf16x8 bK = *(const bf16x8*)&kv[(nt * 16 + l15) * 72 + ks * 32 + quad * 8];
        a = mfma16(aQ[qt][ks], bK, a);
      }
      sreg[nt] = a;
    }
    const int qlb = wv * 32 + qt * 16 + quad * 4;
    float rinv[4];
#pragma unroll
    for (int r = 0; r < 4; ++r) {
      const int ql = qlb + r;
      float sum = 0.f;
#pragma unroll
      for (int nt = 0; nt < 16; ++nt) {
        const int j = nt * 16 + l15;
        const bool valid = (nt < 8) ? (w > 0) : (ql >= j - WIN);
        const float p = valid ? __expf(sreg[nt][r]) : 0.0f;   // no max-sub: |s|<=8
        sreg[nt][r] = p;
        sum += p;
      }
#pragma unroll
      for (int m = 8; m; m >>= 1) sum += __shfl_xor(sum, m);
      rinv[r] = 1.0f / sum;
    }
#pragma unroll
    for (int half = 0; half < 2; ++half) {
#pragma unroll
      for (int ntw = 0; ntw < 8; ++ntw)
#pragma unroll
        for (int r = 0; r < 4; ++r)
          pbuf[wv][(quad * 4 + r) * 136 + ntw * 16 + l15] =
              (bf16)(sreg[half * 8 + ntw][r] * rinv[r]);
#pragma unroll
      for (int kk = 0; kk < 4; ++kk)
        aP[qt][half * 4 + kk] = *(const bf16x8*)&pbuf[wv][l15 * 136 + kk * 32 + quad * 8];
    }
  }
  __syncthreads();

#pragma unroll
  for (int dg = 0; dg < 8; ++dg)
#pragma unroll
    for (int i = 0; i < 8; ++i)
      kv[(dg * 8 + i) * 264 + tid] = vld[dg][i];
  __syncthreads();

#pragma unroll
  for (int qt = 0; qt < 2; ++qt) {
#pragma unroll
    for (int dt = 0; dt < 4; ++dt) {
      f32x4 o = {0.f, 0.f, 0.f, 0.f};
#pragma unroll
      for (int ks2 = 0; ks2 < 8; ++ks2) {
        bf16x8 bV = *(const bf16x8*)&kv[(dt * 16 + l15) * 264 + ks2 * 32 + quad * 8];
        o = mfma16(aP[qt][ks2], bV, o);
      }
#pragma unroll
      for (int r = 0; r < 4; ++r)
        pbuf[wv][(quad * 4 + r) * 136 + dt * 16 + l15] = (bf16)o[r];
    }
#pragma unroll
    for (int t = 0; t < 2; ++t) {
      const int rr = t * 8 + (lane >> 3), ch = lane & 7;
      bf16x8 ov = *(const bf16x8*)&pbuf[wv][rr * 136 + ch * 8];
      const int tok = w * WIN + wv * 32 + qt * 16 + rr;
      *(bf16x8*)(ao + ((size_t)b * SEQ + tok) * DIM + h * DH + ch * 8) = ov;
    }
  }
}

extern "C" void kernel_launch(void* const* d_in, const int* in_sizes, int n_in,
                              void* d_out, int out_size, void* d_ws, size_t ws_size,
                              hipStream_t stream) {
  (void)in_sizes; (void)n_in; (void)out_size;
  float* out = (float*)d_out;                      // fp32 output per reference dtype
  bf16* cano = (bf16*)d_ws;
  const unsigned short* probe = (const unsigned short*)d_in[2];

  SrcPtrs sp;
  for (int i = 0; i < 12; ++i) sp.p[i] = d_in[i];

  bf16* slot0 = cano + P_EL;             // h -> ao -> hf
  bf16* slot1 = cano + P_EL + R_EL;      // q -> x2
  bf16* slot2 = cano + P_EL + 2 * R_EL;  // k ; later f1
  bf16* slot3 = cano + P_EL + 3 * R_EL;  // v (natural head-major layout)

  const bf16* qsc  = cano + C_SM + 0;
  const bf16* ksc  = cano + C_SM + 64;
  const bf16* bout = cano + C_SM + 128;
  const bf16* l1g  = cano + C_SM + 640;
  const bf16* l1b  = cano + C_SM + 1152;
  const bf16* lfg  = cano + C_SM + 1664;
  const bf16* lfb  = cano + C_SM + 2176;

  constexpr int LDSB = 3 * 12288 * 2;    // 73728 B dynamic LDS for gemm_bt
  constexpr int LDSF = 3 * 16384 * 2;    // 98304 B dynamic LDS for gemm_ff
  static bool attr_done = false;
  if (!attr_done) {
    hipFuncSetAttribute((const void*)gemm_bt<0>, hipFuncAttributeMaxDynamicSharedMemorySize, LDSB);
    hipFuncSetAttribute((const void*)gemm_bt<1>, hipFuncAttributeMaxDynamicSharedMemorySize, LDSB);
    hipFuncSetAttribute((const void*)gemm_ff<2>, hipFuncAttributeMaxDynamicSharedMemorySize, LDSF);
    hipFuncSetAttribute((const void*)gemm_ff<3>, hipFuncAttributeMaxDynamicSharedMemorySize, LDSF);
    hipFuncSetAttribute((const void*)gemm_ff<4>, hipFuncAttributeMaxDynamicSharedMemorySize, LDSF);
    attr_done = true;
  }

  ingest_kernel<<<1538, 256, 0, stream>>>(sp, cano);
  ln_kernel<<<TOK / 4, 256, 0, stream>>>(d_in[0], l1g, l1b, slot0, probe, 1);
  gemm_bt<0><<<16 * 96, 512, LDSB, stream>>>(slot0, cano + C_QKV, slot1, slot2, slot3,
                                             nullptr, nullptr, qsc, ksc, probe,
                                             DIM, DIM, 0, 12);
  attn_kernel<<<dim3(NW, HEADS, BATCH), 256, 0, stream>>>(slot1, slot2, slot3, slot0);
  gemm_bt<1><<<16 * 32, 512, LDSB, stream>>>(slot0, cano + C_WOUT, slot1, nullptr, nullptr,
                                             nullptr, d_in[0], nullptr, bout, probe,
                                             DIM, DIM, 0, 4);
  ln_kernel<<<TOK / 4, 256, 0, stream>>>(slot1, lfg, lfb, slot0, probe, 0);

  const bool big = ws_size >= (size_t)(P_EL + 6 * R_EL) * 2;
  if (big) {
    bf16* f1 = slot2;                    // spans slot2..slot5 (4R)
    gemm_ff<2><<<16 * 64, 512, LDSF, stream>>>(slot0, cano + C_WF1, f1, nullptr, nullptr,
                                               DIM, DIM, 2048, 8);
    gemm_ff<3><<<16 * 16, 512, LDSF, stream>>>(f1, cano + C_WF2, nullptr, out, slot1,
                                               2048, 2048, 0, 2);
  } else {
    bf16* f1h = slot2;                   // TOK x 1024 bf16 = 2R
    for (int half = 0; half < 2; ++half) {
      const bf16* w1h = cano + C_WF1 + (size_t)half * 1024 * DIM;
      const bf16* w2h = cano + C_WF2 + (size_t)half * 1024;
      gemm_ff<2><<<16 * 32, 512, LDSF, stream>>>(slot0, w1h, f1h, nullptr, nullptr,
                                                 DIM, DIM, 1024, 4);
      if (half == 0)
        gemm_ff<3><<<16 * 16, 512, LDSF, stream>>>(f1h, w2h, nullptr, out, slot1,
                                                   1024, 2048, 0, 2);
      else
        gemm_ff<4><<<16 * 16, 512, LDSF, stream>>>(f1h, w2h, nullptr, out, nullptr,
                                                   1024, 2048, 0, 2);
    }
  }
}